// Round 4
// baseline (69.888 us; speedup 1.0000x reference)
//
#include <hip/hip_runtime.h>
#include <math.h>

// Problem geometry
#define NC   65536              // curves
#define NL   256                // points per curve
#define NTOT (NC * NL)
#define CPW  8                  // curves per wave
#define WPB  4                  // waves per block (256 threads)
#define NBLK (NC / (CPW * WPB)) // 2048 blocks
#define NSTAT 7

// stat slots: 0=A(merged sq*10/N + rAp + pen + srd) 1=sw 2=sx 3=sy 4=sxy 5=sxx 6=syy

__global__ __launch_bounds__(256) void loss_main(
    const float* __restrict__ An, const float* __restrict__ Ac,
    const float* __restrict__ Aj, const float* __restrict__ Ap,
    const float* __restrict__ Ar, const float* __restrict__ Ci,
    const float* __restrict__ Vc, const float* __restrict__ Jm,
    const float* __restrict__ Rd, const int* __restrict__ msk,
    float* __restrict__ ws)
{
    const int lane = threadIdx.x & 63;
    const int wid  = threadIdx.x >> 6;
    const int l    = lane & 15;          // lane within 16-lane group
    const int g    = lane >> 4;          // group id 0..3 (curve within quad)
    const int c0   = (blockIdx.x * WPB + wid) * CPW;   // first curve of wave

    // ---- per-curve preload: lane i (<CPW) owns curve c0+i ----
    float wmask = 0.f, fitw = 0.f, srd = 0.f;
    float sw=0.f, sx=0.f, sy=0.f, sxy=0.f, sxx=0.f, syy=0.f;
    if (lane < CPW) {
        const int c = c0 + lane;
        const int m = msk[c];
        const float x = Jm[c], y = Vc[c], rd = Rd[c];
        const float ci = Ci[(size_t)c * NL + (NL - 1)];
        wmask = (m == 0) ? 1.f : 0.f;
        fitw  = (ci > 500.f) ? 0.15f * wmask : 0.f;
        srd   = fmaxf(-rd, 0.f);
        sw = wmask; sx = wmask * x; sy = wmask * y;
        sxy = wmask * x * y; sxx = wmask * x * x; syy = wmask * y * y;
    }

    float sq = 0.f, rAp = 0.f, pen = 0.f;

#pragma unroll 1
    for (int k = 0; k < CPW / 4; ++k) {
        const int c = c0 + k * 4 + g;
        const size_t off = (size_t)c * NL + (size_t)(l << 2);
        const float4* pAn = (const float4*)(An + off);
        const float4* pAr = (const float4*)(Ar + off);
        const float4* pAc = (const float4*)(Ac + off);
        const float4* pAj = (const float4*)(Aj + off);
        const float4* pAp = (const float4*)(Ap + off);
        // 20 independent float4 loads (lane covers elements j*64 + l*4 + 0..3)
        float4 an0=pAn[0], an1=pAn[16], an2=pAn[32], an3=pAn[48];
        float4 ar0=pAr[0], ar1=pAr[16], ar2=pAr[32], ar3=pAr[48];
        float4 ac0=pAc[0], ac1=pAc[16], ac2=pAc[32], ac3=pAc[48];
        float4 aj0=pAj[0], aj1=pAj[16], aj2=pAj[32], aj3=pAj[48];
        float4 ap0=pAp[0], ap1=pAp[16], ap2=pAp[32], ap3=pAp[48];

        float lsAj = 0.f, lsAc = 0.f;
        float bestv = 3.402823466e38f; int besti = 0;
        float aj_at = 0.f, ap_at = 0.f;

#define PR(AN,AR,AC,AJ,AP,CMP,JJ,CC)                                   \
        { float d = AN.CMP - AR.CMP; sq = fmaf(d, d, sq);              \
          rAp += fmaxf(-AP.CMP, 0.f);                                  \
          float acj = AC.CMP - AJ.CMP;                                 \
          lsAj += fmaxf(-acj, 0.f); lsAc += fmaxf(acj, 0.f);           \
          float a = fabsf(acj);                                        \
          if (a < bestv) { bestv = a; besti = (JJ)*64 + (l<<2) + (CC); \
                           aj_at = AJ.CMP; ap_at = AP.CMP; } }
        PR(an0,ar0,ac0,aj0,ap0,x,0,0) PR(an0,ar0,ac0,aj0,ap0,y,0,1)
        PR(an0,ar0,ac0,aj0,ap0,z,0,2) PR(an0,ar0,ac0,aj0,ap0,w,0,3)
        PR(an1,ar1,ac1,aj1,ap1,x,1,0) PR(an1,ar1,ac1,aj1,ap1,y,1,1)
        PR(an1,ar1,ac1,aj1,ap1,z,1,2) PR(an1,ar1,ac1,aj1,ap1,w,1,3)
        PR(an2,ar2,ac2,aj2,ap2,x,2,0) PR(an2,ar2,ac2,aj2,ap2,y,2,1)
        PR(an2,ar2,ac2,aj2,ap2,z,2,2) PR(an2,ar2,ac2,aj2,ap2,w,2,3)
        PR(an3,ar3,ac3,aj3,ap3,x,3,0) PR(an3,ar3,ac3,aj3,ap3,y,3,1)
        PR(an3,ar3,ac3,aj3,ap3,z,3,2) PR(an3,ar3,ac3,aj3,ap3,w,3,3)
#undef PR

        // 4-stage butterfly within the 16-lane group: argmin + two sums
#pragma unroll
        for (int s = 1; s < 16; s <<= 1) {
            float ov  = __shfl_xor(bestv, s);
            int   oi  = __shfl_xor(besti, s);
            float oaj = __shfl_xor(aj_at, s);
            float oap = __shfl_xor(ap_at, s);
            if (ov < bestv || (ov == bestv && oi < besti)) {
                bestv = ov; besti = oi; aj_at = oaj; ap_at = oap;
            }
            lsAj += __shfl_xor(lsAj, s);
            lsAc += __shfl_xor(lsAc, s);
        }

        // fetch this curve's mask weights from the preload lanes (uniform per group)
        const int srcl = k * 4 + g;
        const float wv = __shfl(wmask, srcl);
        const float fw = __shfl(fitw,  srcl);

        if (l == 0) {
            pen += 3.f * fmaxf(1.1f * aj_at - ap_at, 0.f);
            pen += wv * (fmaxf(8.f - lsAj, 0.f) + fmaxf(8.f - lsAc, 0.f));
        }
        if (l == 15) {   // holds elements 252..255; end = .w of j=3
            pen += fmaxf(aj3.w - ac3.w, 0.f);
            pen += fw * fmaxf(ap3.w - aj3.w, 0.f);
        }
    }

    // ---- merge simple-sum stats into one accumulator, then wave reduce ----
    float A = fmaf(sq, 10.f / (float)NTOT, rAp + pen + srd);
    float st[NSTAT] = {A, sw, sx, sy, sxy, sxx, syy};
#pragma unroll
    for (int j = 0; j < NSTAT; ++j) {
#pragma unroll
        for (int s = 1; s < 64; s <<= 1) st[j] += __shfl_xor(st[j], s);
    }

    __shared__ float sred[WPB][NSTAT];
    if (lane == 0) {
#pragma unroll
        for (int j = 0; j < NSTAT; ++j) sred[wid][j] = st[j];
    }
    __syncthreads();
    if (threadIdx.x == 0) {
#pragma unroll
        for (int j = 0; j < NSTAT; ++j) {
            float v = sred[0][j] + sred[1][j] + sred[2][j] + sred[3][j];
            ws[j * NBLK + blockIdx.x] = v;
        }
    }
}

__global__ __launch_bounds__(256) void loss_final(
    const float* __restrict__ ws,
    const float* __restrict__ dHaV, const float* __restrict__ dHaJ,
    const float* __restrict__ dHaT,
    const float* __restrict__ ToV,  const float* __restrict__ ToJ,
    const float* __restrict__ ToT,
    float* __restrict__ out)
{
    __shared__ float red[NSTAT][256];
    const int t = threadIdx.x;
    float p[NSTAT];
#pragma unroll
    for (int j = 0; j < NSTAT; ++j) p[j] = 0.f;
    for (int k = 0; k < NBLK / 256; ++k) {
        int b = t + k * 256;
#pragma unroll
        for (int j = 0; j < NSTAT; ++j) p[j] += ws[j * NBLK + b];
    }
#pragma unroll
    for (int j = 0; j < NSTAT; ++j) red[j][t] = p[j];
    __syncthreads();
    for (int s = 128; s > 0; s >>= 1) {
        if (t < s) {
#pragma unroll
            for (int j = 0; j < NSTAT; ++j) red[j][t] += red[j][t + s];
        }
        __syncthreads();
    }
    if (t == 0) {
        float A   = red[0][0];
        float sw  = red[1][0], sx  = red[2][0], sy  = red[3][0];
        float sxy = red[4][0], sxx = red[5][0], syy = red[6][0];

        float loss = A;

        // Pearson correlation over masked curves (one-pass identity)
        float cnum = sxy - sx * sy / sw;
        float cden = sqrtf(sxx - sx * sx / sw) * sqrtf(syy - sy * sy / sw);
        float cost = cnum / cden;
        if (!(cost == cost)) cost = 0.f;       // NaN -> 0
        cost = fminf(cost, 0.7f);
        loss += 0.7f - cost;

        float fg = 0.f;
#pragma unroll
        for (int i = 0; i < 4; ++i) {
            fg += 10.f * fmaxf(-dHaV[i], 0.f);
            fg += fmaxf(-dHaJ[i], 0.f);
            fg += fmaxf(-dHaT[i], 0.f);
            fg += fmaxf(273.15f - ToV[i], 0.f);
            fg += fmaxf(273.15f - ToJ[i], 0.f);
            fg += fmaxf(273.15f - ToT[i], 0.f);
        }
        loss += fg;

        out[0] = loss;
    }
}

extern "C" void kernel_launch(void* const* d_in, const int* in_sizes, int n_in,
                              void* d_out, int out_size, void* d_ws, size_t ws_size,
                              hipStream_t stream) {
    const float* An  = (const float*)d_in[0];
    const float* Ac  = (const float*)d_in[1];
    const float* Aj  = (const float*)d_in[2];
    const float* Ap  = (const float*)d_in[3];
    const float* Ar  = (const float*)d_in[4];
    const float* Ci  = (const float*)d_in[5];
    const float* Vc  = (const float*)d_in[6];
    const float* Jm  = (const float*)d_in[7];
    const float* Rd  = (const float*)d_in[8];
    const float* dHaV = (const float*)d_in[9];
    const float* dHaJ = (const float*)d_in[10];
    const float* dHaT = (const float*)d_in[11];
    const float* ToV  = (const float*)d_in[12];
    const float* ToJ  = (const float*)d_in[13];
    const float* ToT  = (const float*)d_in[14];
    const int*   msk  = (const int*)d_in[15];

    float* ws  = (float*)d_ws;           // NSTAT * NBLK floats = 56 KB
    float* out = (float*)d_out;

    loss_main<<<NBLK, 256, 0, stream>>>(An, Ac, Aj, Ap, Ar, Ci, Vc, Jm, Rd, msk, ws);
    loss_final<<<1, 256, 0, stream>>>(ws, dHaV, dHaJ, dHaT, ToV, ToJ, ToT, out);
}

// Round 7
// 65.725 us; speedup vs baseline: 1.0633x; 1.0633x over previous
//
#include <hip/hip_runtime.h>
#include <math.h>

// Problem geometry
#define NC   65536              // curves
#define NL   256                // points per curve
#define NTOT (NC * NL)
#define WPB  4                  // waves per block (256 threads)
#define CPW  4                  // curves per wave (one-shot burst)
#define NBLK (NC / (WPB * CPW)) // 4096 blocks
#define NSTAT 7

// stat slots: 0=A(merged) 1=sw 2=sx 3=sy 4=sxy 5=sxx 6=syy

__global__ __launch_bounds__(256, 4) void loss_main(
    const float* __restrict__ An, const float* __restrict__ Ac,
    const float* __restrict__ Aj, const float* __restrict__ Ap,
    const float* __restrict__ Ar, const float* __restrict__ Ci,
    const float* __restrict__ Vc, const float* __restrict__ Jm,
    const float* __restrict__ Rd, const int* __restrict__ msk,
    float* __restrict__ ws)
{
    const int lane = threadIdx.x & 63;
    const int wid  = threadIdx.x >> 6;
    const int l    = lane & 15;          // lane within 16-lane group
    const int g    = lane >> 4;          // group id 0..3
    const int c0   = (blockIdx.x * WPB + wid) * CPW;
    const int c    = c0 + g;             // this group's curve
    const size_t off = (size_t)c * NL + (size_t)(l << 2);

    // ---- one burst: 20 independent 16B loads (elements j*64 + l*4 + 0..3) ----
    const float4* pAn = (const float4*)(An + off);
    const float4* pAr = (const float4*)(Ar + off);
    const float4* pAc = (const float4*)(Ac + off);
    const float4* pAj = (const float4*)(Aj + off);
    const float4* pAp = (const float4*)(Ap + off);
    float4 an0=pAn[0], an1=pAn[16], an2=pAn[32], an3=pAn[48];
    float4 ar0=pAr[0], ar1=pAr[16], ar2=pAr[32], ar3=pAr[48];
    float4 ac0=pAc[0], ac1=pAc[16], ac2=pAc[32], ac3=pAc[48];
    float4 aj0=pAj[0], aj1=pAj[16], aj2=pAj[32], aj3=pAj[48];
    float4 ap0=pAp[0], ap1=pAp[16], ap2=pAp[32], ap3=pAp[48];

    // per-curve scalar loads (lanes 0..3), issued alongside the burst
    int   m  = 0;
    float xv = 0.f, yv = 0.f, rd = 0.f, ci = 0.f;
    if (lane < CPW) {
        const int cc2 = c0 + lane;
        m  = msk[cc2];
        xv = Jm[cc2]; yv = Vc[cc2]; rd = Rd[cc2];
        ci = Ci[(size_t)cc2 * NL + (NL - 1)];
    }

    float sq = 0.f, rAp = 0.f, pen = 0.f;
    float lsAj = 0.f, lsAc = 0.f, T1 = 0.f, T2 = 0.f;
    unsigned key = 0xFFFFFFFFu;

#define PR(AN,AR,AC,AJ,AP,CMP,JJ,CC)                                        \
    { float d = AN.CMP - AR.CMP; sq = fmaf(d, d, sq);                       \
      rAp += fmaxf(-AP.CMP, 0.f);                                           \
      float acj = AC.CMP - AJ.CMP;                                          \
      lsAj += fmaxf(-acj, 0.f); lsAc += fmaxf(acj, 0.f);                    \
      unsigned kb = (__float_as_uint(fabsf(acj)) & 0xFFFFFF00u)             \
                    | (unsigned)((JJ)*64 + (l<<2) + (CC));                  \
      key = key < kb ? key : kb; }
    PR(an0,ar0,ac0,aj0,ap0,x,0,0) PR(an0,ar0,ac0,aj0,ap0,y,0,1)
    PR(an0,ar0,ac0,aj0,ap0,z,0,2) PR(an0,ar0,ac0,aj0,ap0,w,0,3)
    PR(an1,ar1,ac1,aj1,ap1,x,1,0) PR(an1,ar1,ac1,aj1,ap1,y,1,1)
    PR(an1,ar1,ac1,aj1,ap1,z,1,2) PR(an1,ar1,ac1,aj1,ap1,w,1,3)
    PR(an2,ar2,ac2,aj2,ap2,x,2,0) PR(an2,ar2,ac2,aj2,ap2,y,2,1)
    PR(an2,ar2,ac2,aj2,ap2,z,2,2) PR(an2,ar2,ac2,aj2,ap2,w,2,3)
    PR(an3,ar3,ac3,aj3,ap3,x,3,0) PR(an3,ar3,ac3,aj3,ap3,y,3,1)
    PR(an3,ar3,ac3,aj3,ap3,z,3,2) PR(an3,ar3,ac3,aj3,ap3,w,3,3)
#undef PR

    // 4-stage butterfly within the 16-lane group: packed-key argmin + two sums
#pragma unroll
    for (int s = 1; s < 16; s <<= 1) {
        unsigned ok = __shfl_xor(key, s);
        key = key < ok ? key : ok;
        lsAj += __shfl_xor(lsAj, s);
        lsAc += __shfl_xor(lsAc, s);
    }

    // resolve Aj/Ap at argmin: owner lane selects its component, then broadcast
    const int idx = (int)(key & 255u);
    const int jj  = idx >> 6;
    const int lo  = (idx >> 2) & 15;
    const int cc  = idx & 3;
#define PICK(V) (cc==0 ? (V).x : cc==1 ? (V).y : cc==2 ? (V).z : (V).w)
    float selA = jj==0 ? PICK(aj0) : jj==1 ? PICK(aj1) : jj==2 ? PICK(aj2) : PICK(aj3);
    float selP = jj==0 ? PICK(ap0) : jj==1 ? PICK(ap1) : jj==2 ? PICK(ap2) : PICK(ap3);
#undef PICK
    const float aj_at = __shfl(selA, (g << 4) + lo);
    const float ap_at = __shfl(selP, (g << 4) + lo);

    if (l == 0) {
        pen += 3.f * fmaxf(1.1f * aj_at - ap_at, 0.f);
        T1 = fmaxf(8.f - lsAj, 0.f) + fmaxf(8.f - lsAc, 0.f);
    }
    if (l == 15) {   // elements 252..255 live here; end = .w of j=3
        pen += fmaxf(aj3.w - ac3.w, 0.f);
        T2 = fmaxf(ap3.w - aj3.w, 0.f);
    }

    // ---- epilogue: per-curve masked stats on lanes 0..3 ----
    const int q = lane & 3;
    const float T1g = __shfl(T1, q << 4);
    const float T2g = __shfl(T2, (q << 4) + 15);
    float sw=0.f, sx=0.f, sy=0.f, sxy=0.f, sxx=0.f, syy=0.f;
    if (lane < CPW) {
        const float wm = (m == 0) ? 1.f : 0.f;
        const float fw = (ci > 500.f) ? 0.15f * wm : 0.f;
        pen += wm * T1g + fw * T2g + fmaxf(-rd, 0.f);
        sw = wm; sx = wm * xv; sy = wm * yv;
        sxy = wm * xv * yv; sxx = wm * xv * xv; syy = wm * yv * yv;
    }

    // merged simple-sum stat: full-wave reduce
    float A = fmaf(sq, 10.f / (float)NTOT, rAp + pen);
#pragma unroll
    for (int s = 1; s < 64; s <<= 1) A += __shfl_xor(A, s);
    // corr stats live only on lanes 0..3: 2-stage reduce
#pragma unroll
    for (int s = 1; s < 4; s <<= 1) {
        sw  += __shfl_xor(sw,  s);
        sx  += __shfl_xor(sx,  s);
        sy  += __shfl_xor(sy,  s);
        sxy += __shfl_xor(sxy, s);
        sxx += __shfl_xor(sxx, s);
        syy += __shfl_xor(syy, s);
    }

    __shared__ float sred[WPB][NSTAT];
    if (lane == 0) {
        sred[wid][0] = A;   sred[wid][1] = sw;  sred[wid][2] = sx;
        sred[wid][3] = sy;  sred[wid][4] = sxy; sred[wid][5] = sxx;
        sred[wid][6] = syy;
    }
    __syncthreads();
    if (threadIdx.x == 0) {
#pragma unroll
        for (int j = 0; j < NSTAT; ++j) {
            float v = sred[0][j] + sred[1][j] + sred[2][j] + sred[3][j];
            ws[j * NBLK + blockIdx.x] = v;
        }
    }
}

__global__ __launch_bounds__(256) void loss_final(
    const float* __restrict__ ws,
    const float* __restrict__ dHaV, const float* __restrict__ dHaJ,
    const float* __restrict__ dHaT,
    const float* __restrict__ ToV,  const float* __restrict__ ToJ,
    const float* __restrict__ ToT,
    float* __restrict__ out)
{
    __shared__ float red[NSTAT][256];
    const int t = threadIdx.x;
    float p[NSTAT];
#pragma unroll
    for (int j = 0; j < NSTAT; ++j) p[j] = 0.f;
    for (int k = 0; k < NBLK / 256; ++k) {
        int b = t + k * 256;
#pragma unroll
        for (int j = 0; j < NSTAT; ++j) p[j] += ws[j * NBLK + b];
    }
#pragma unroll
    for (int j = 0; j < NSTAT; ++j) red[j][t] = p[j];
    __syncthreads();
    for (int s = 128; s > 0; s >>= 1) {
        if (t < s) {
#pragma unroll
            for (int j = 0; j < NSTAT; ++j) red[j][t] += red[j][t + s];
        }
        __syncthreads();
    }
    if (t == 0) {
        float A   = red[0][0];
        float sw  = red[1][0], sx  = red[2][0], sy  = red[3][0];
        float sxy = red[4][0], sxx = red[5][0], syy = red[6][0];

        float loss = A;

        // Pearson correlation over masked curves (one-pass identity)
        float cnum = sxy - sx * sy / sw;
        float cden = sqrtf(sxx - sx * sx / sw) * sqrtf(syy - sy * sy / sw);
        float cost = cnum / cden;
        if (!(cost == cost)) cost = 0.f;       // NaN -> 0
        cost = fminf(cost, 0.7f);
        loss += 0.7f - cost;

        float fg = 0.f;
#pragma unroll
        for (int i = 0; i < 4; ++i) {
            fg += 10.f * fmaxf(-dHaV[i], 0.f);
            fg += fmaxf(-dHaJ[i], 0.f);
            fg += fmaxf(-dHaT[i], 0.f);
            fg += fmaxf(273.15f - ToV[i], 0.f);
            fg += fmaxf(273.15f - ToJ[i], 0.f);
            fg += fmaxf(273.15f - ToT[i], 0.f);
        }
        loss += fg;

        out[0] = loss;
    }
}

extern "C" void kernel_launch(void* const* d_in, const int* in_sizes, int n_in,
                              void* d_out, int out_size, void* d_ws, size_t ws_size,
                              hipStream_t stream) {
    const float* An  = (const float*)d_in[0];
    const float* Ac  = (const float*)d_in[1];
    const float* Aj  = (const float*)d_in[2];
    const float* Ap  = (const float*)d_in[3];
    const float* Ar  = (const float*)d_in[4];
    const float* Ci  = (const float*)d_in[5];
    const float* Vc  = (const float*)d_in[6];
    const float* Jm  = (const float*)d_in[7];
    const float* Rd  = (const float*)d_in[8];
    const float* dHaV = (const float*)d_in[9];
    const float* dHaJ = (const float*)d_in[10];
    const float* dHaT = (const float*)d_in[11];
    const float* ToV  = (const float*)d_in[12];
    const float* ToJ  = (const float*)d_in[13];
    const float* ToT  = (const float*)d_in[14];
    const int*   msk  = (const int*)d_in[15];

    float* ws  = (float*)d_ws;           // NSTAT * NBLK floats = 114 KB
    float* out = (float*)d_out;

    loss_main<<<NBLK, 256, 0, stream>>>(An, Ac, Aj, Ap, Ar, Ci, Vc, Jm, Rd, msk, ws);
    loss_final<<<1, 256, 0, stream>>>(ws, dHaV, dHaJ, dHaT, ToV, ToJ, ToT, out);
}

// Round 9
// 64.350 us; speedup vs baseline: 1.0861x; 1.0214x over previous
//
#include <hip/hip_runtime.h>
#include <math.h>

// Problem geometry
#define NC   65536              // curves
#define NL   256                // points per curve
#define NTOT (NC * NL)
#define WPB  4                  // waves per block (256 threads)
#define CPW  8                  // curves per wave (sequential, dbuf-pipelined)
#define NBLK (NC / (WPB * CPW)) // 2048 blocks
#define NSTAT 7

// stat slots: 0=A(merged) 1=sw 2=sx 3=sy 4=sxy 5=sxx 6=syy

__global__ __launch_bounds__(256, 4) void loss_main(
    const float* __restrict__ An, const float* __restrict__ Ac,
    const float* __restrict__ Aj, const float* __restrict__ Ap,
    const float* __restrict__ Ar, const float* __restrict__ Ci,
    const float* __restrict__ Vc, const float* __restrict__ Jm,
    const float* __restrict__ Rd, const int* __restrict__ msk,
    float* __restrict__ ws)
{
    const int lane = threadIdx.x & 63;
    const int wid  = threadIdx.x >> 6;
    const int c0   = (blockIdx.x * WPB + wid) * CPW;

    // accumulators
    float sq = 0.f, rAp = 0.f, pen = 0.f;
    float sw=0.f, sx=0.f, sy=0.f, sxy=0.f, sxx=0.f, syy=0.f;  // lane-0 only

    // double-buffered tiles: one curve per wave, lane covers elems lane*4..+3
    float4 anA, arA, acA, ajA, apA, anB, arB, acB, ajB, apB;
    int   mA,  mB;
    float xA, yA, rdA, ciA, xB, yB, rdB, ciB;

#define LOADT(S, c) { const size_t o = (size_t)(c) * NL + (size_t)(lane << 2); \
        an##S = *(const float4*)(An + o); ar##S = *(const float4*)(Ar + o);    \
        ac##S = *(const float4*)(Ac + o); aj##S = *(const float4*)(Aj + o);    \
        ap##S = *(const float4*)(Ap + o); }
#define LOADS(S, c) { m##S = msk[c]; x##S = Jm[c]; y##S = Vc[c];               \
        rd##S = Rd[c]; ci##S = Ci[(size_t)(c) * NL + (NL - 1)]; }

    auto process = [&](const float4& an, const float4& ar, const float4& ac,
                       const float4& aj, const float4& ap, int m, float xv,
                       float yv, float rd, float ci) {
        float d;
        d = an.x - ar.x; sq = fmaf(d, d, sq);
        d = an.y - ar.y; sq = fmaf(d, d, sq);
        d = an.z - ar.z; sq = fmaf(d, d, sq);
        d = an.w - ar.w; sq = fmaf(d, d, sq);

        float lsAj = 0.f, lsAc = 0.f;
        unsigned key = 0xFFFFFFFFu;
#define COMP(ACV, AJV, APV, J)                                                 \
        { rAp += fmaxf(-(APV), 0.f);                                           \
          float acj = (ACV) - (AJV);                                           \
          lsAj += fmaxf(-acj, 0.f); lsAc += fmaxf(acj, 0.f);                   \
          unsigned kb = (__float_as_uint(fabsf(acj)) & 0xFFFFFF00u)            \
                        | (unsigned)((lane << 2) + (J));                       \
          key = key < kb ? key : kb; }
        COMP(ac.x, aj.x, ap.x, 0)
        COMP(ac.y, aj.y, ap.y, 1)
        COMP(ac.z, aj.z, ap.z, 2)
        COMP(ac.w, aj.w, ap.w, 3)
#undef COMP

        // full-wave butterfly: packed-key argmin (first-index ties) + 2 sums
#pragma unroll
        for (int s = 1; s < 64; s <<= 1) {
            unsigned ok = __shfl_xor(key, s);
            key = key < ok ? key : ok;
            lsAj += __shfl_xor(lsAj, s);
            lsAc += __shfl_xor(lsAc, s);
        }

        const int idx = (int)(key & 255u);
        const int lo  = idx >> 2;
        const int cc  = idx & 3;
        float selA = cc==0 ? aj.x : cc==1 ? aj.y : cc==2 ? aj.z : aj.w;
        float selP = cc==0 ? ap.x : cc==1 ? ap.y : cc==2 ? ap.z : ap.w;
        const float aj_at = __shfl(selA, lo);
        const float ap_at = __shfl(selP, lo);

        const float wm = (m == 0) ? 1.f : 0.f;
        const float fw = (ci > 500.f) ? 0.15f * wm : 0.f;
        if (lane == 0) {
            pen += 3.f * fmaxf(1.1f * aj_at - ap_at, 0.f);
            pen += wm * (fmaxf(8.f - lsAj, 0.f) + fmaxf(8.f - lsAc, 0.f));
            pen += fmaxf(-rd, 0.f);
            sw += wm;      sx += wm * xv;       sy += wm * yv;
            sxy = fmaf(wm * xv, yv, sxy);
            sxx = fmaf(wm * xv, xv, sxx);
            syy = fmaf(wm * yv, yv, syy);
        }
        if (lane == 63) {   // elements 252..255; end-of-curve = .w
            pen += fmaxf(aj.w - ac.w, 0.f);
            pen += fw * fmaxf(ap.w - aj.w, 0.f);
        }
    };

    // ---- software-pipelined main loop: issue next tile before consuming ----
    LOADT(A, c0) LOADS(A, c0)
#pragma unroll 1
    for (int k = 0; k < CPW; k += 2) {
        LOADT(B, c0 + k + 1) LOADS(B, c0 + k + 1)
        process(anA, arA, acA, ajA, apA, mA, xA, yA, rdA, ciA);
        if (k + 2 < CPW) { LOADT(A, c0 + k + 2) LOADS(A, c0 + k + 2) }
        process(anB, arB, acB, ajB, apB, mB, xB, yB, rdB, ciB);
    }
#undef LOADT
#undef LOADS

    // merged simple-sum stat: full-wave reduce
    float A = fmaf(sq, 10.f / (float)NTOT, rAp + pen);
#pragma unroll
    for (int s = 1; s < 64; s <<= 1) A += __shfl_xor(A, s);

    __shared__ float sred[WPB][NSTAT];
    if (lane == 0) {
        sred[wid][0] = A;   sred[wid][1] = sw;  sred[wid][2] = sx;
        sred[wid][3] = sy;  sred[wid][4] = sxy; sred[wid][5] = sxx;
        sred[wid][6] = syy;
    }
    __syncthreads();
    if (threadIdx.x == 0) {
#pragma unroll
        for (int j = 0; j < NSTAT; ++j) {
            float v = sred[0][j] + sred[1][j] + sred[2][j] + sred[3][j];
            ws[j * NBLK + blockIdx.x] = v;
        }
    }
}

__global__ __launch_bounds__(256) void loss_final(
    const float* __restrict__ ws,
    const float* __restrict__ dHaV, const float* __restrict__ dHaJ,
    const float* __restrict__ dHaT,
    const float* __restrict__ ToV,  const float* __restrict__ ToJ,
    const float* __restrict__ ToT,
    float* __restrict__ out)
{
    __shared__ float red[NSTAT][256];
    const int t = threadIdx.x;
    float p[NSTAT];
#pragma unroll
    for (int j = 0; j < NSTAT; ++j) p[j] = 0.f;
    for (int k = 0; k < NBLK / 256; ++k) {
        int b = t + k * 256;
#pragma unroll
        for (int j = 0; j < NSTAT; ++j) p[j] += ws[j * NBLK + b];
    }
#pragma unroll
    for (int j = 0; j < NSTAT; ++j) red[j][t] = p[j];
    __syncthreads();
    for (int s = 128; s > 0; s >>= 1) {
        if (t < s) {
#pragma unroll
            for (int j = 0; j < NSTAT; ++j) red[j][t] += red[j][t + s];
        }
        __syncthreads();
    }
    if (t == 0) {
        float A   = red[0][0];
        float sw  = red[1][0], sx  = red[2][0], sy  = red[3][0];
        float sxy = red[4][0], sxx = red[5][0], syy = red[6][0];

        float loss = A;

        // Pearson correlation over masked curves (one-pass identity)
        float cnum = sxy - sx * sy / sw;
        float cden = sqrtf(sxx - sx * sx / sw) * sqrtf(syy - sy * sy / sw);
        float cost = cnum / cden;
        if (!(cost == cost)) cost = 0.f;       // NaN -> 0
        cost = fminf(cost, 0.7f);
        loss += 0.7f - cost;

        float fg = 0.f;
#pragma unroll
        for (int i = 0; i < 4; ++i) {
            fg += 10.f * fmaxf(-dHaV[i], 0.f);
            fg += fmaxf(-dHaJ[i], 0.f);
            fg += fmaxf(-dHaT[i], 0.f);
            fg += fmaxf(273.15f - ToV[i], 0.f);
            fg += fmaxf(273.15f - ToJ[i], 0.f);
            fg += fmaxf(273.15f - ToT[i], 0.f);
        }
        loss += fg;

        out[0] = loss;
    }
}

extern "C" void kernel_launch(void* const* d_in, const int* in_sizes, int n_in,
                              void* d_out, int out_size, void* d_ws, size_t ws_size,
                              hipStream_t stream) {
    const float* An  = (const float*)d_in[0];
    const float* Ac  = (const float*)d_in[1];
    const float* Aj  = (const float*)d_in[2];
    const float* Ap  = (const float*)d_in[3];
    const float* Ar  = (const float*)d_in[4];
    const float* Ci  = (const float*)d_in[5];
    const float* Vc  = (const float*)d_in[6];
    const float* Jm  = (const float*)d_in[7];
    const float* Rd  = (const float*)d_in[8];
    const float* dHaV = (const float*)d_in[9];
    const float* dHaJ = (const float*)d_in[10];
    const float* dHaT = (const float*)d_in[11];
    const float* ToV  = (const float*)d_in[12];
    const float* ToJ  = (const float*)d_in[13];
    const float* ToT  = (const float*)d_in[14];
    const int*   msk  = (const int*)d_in[15];

    float* ws  = (float*)d_ws;           // NSTAT * NBLK floats = 56 KB
    float* out = (float*)d_out;

    loss_main<<<NBLK, 256, 0, stream>>>(An, Ac, Aj, Ap, Ar, Ci, Vc, Jm, Rd, msk, ws);
    loss_final<<<1, 256, 0, stream>>>(ws, dHaV, dHaJ, dHaT, ToV, ToJ, ToT, out);
}

// Round 10
// 58.965 us; speedup vs baseline: 1.1852x; 1.0913x over previous
//
#include <hip/hip_runtime.h>
#include <math.h>

// Problem geometry
#define NC   65536              // curves
#define NL   256                // points per curve
#define NTOT (NC * NL)
#define WPB  4                  // waves per block (256 threads)
#define CPW  8                  // curves per wave (sequential, dbuf-pipelined)
#define NBLK (NC / (WPB * CPW)) // 2048 blocks
#define NSTAT 7

// stat slots: 0=A(merged) 1=sw 2=sx 3=sy 4=sxy 5=sxx 6=syy

// Non-temporal loads: An/Ar/Ci bypass L3 allocation so Ac/Aj/Ap (192 MB)
// fit and persist in the 256 MB Infinity Cache across replays.
typedef float vf4 __attribute__((ext_vector_type(4)));
__device__ __forceinline__ float4 ldnt4(const float* p) {
    vf4 v = __builtin_nontemporal_load((const vf4*)p);
    float4 r; r.x = v.x; r.y = v.y; r.z = v.z; r.w = v.w;
    return r;
}

__global__ __launch_bounds__(256, 4) void loss_main(
    const float* __restrict__ An, const float* __restrict__ Ac,
    const float* __restrict__ Aj, const float* __restrict__ Ap,
    const float* __restrict__ Ar, const float* __restrict__ Ci,
    const float* __restrict__ Vc, const float* __restrict__ Jm,
    const float* __restrict__ Rd, const int* __restrict__ msk,
    float* __restrict__ ws)
{
    const int lane = threadIdx.x & 63;
    const int wid  = threadIdx.x >> 6;
    const int c0   = (blockIdx.x * WPB + wid) * CPW;

    // accumulators
    float sq = 0.f, rAp = 0.f, pen = 0.f;
    float sw=0.f, sx=0.f, sy=0.f, sxy=0.f, sxx=0.f, syy=0.f;  // lane-0 only

    // double-buffered tiles: one curve per wave, lane covers elems lane*4..+3
    float4 anA, arA, acA, ajA, apA, anB, arB, acB, ajB, apB;
    int   mA,  mB;
    float xA, yA, rdA, ciA, xB, yB, rdB, ciB;

#define LOADT(S, c) { const size_t o = (size_t)(c) * NL + (size_t)(lane << 2); \
        an##S = ldnt4(An + o);            ar##S = ldnt4(Ar + o);               \
        ac##S = *(const float4*)(Ac + o); aj##S = *(const float4*)(Aj + o);    \
        ap##S = *(const float4*)(Ap + o); }
#define LOADS(S, c) { m##S = msk[c]; x##S = Jm[c]; y##S = Vc[c];               \
        rd##S = Rd[c];                                                         \
        ci##S = __builtin_nontemporal_load(Ci + (size_t)(c) * NL + (NL - 1)); }

    auto process = [&](const float4& an, const float4& ar, const float4& ac,
                       const float4& aj, const float4& ap, int m, float xv,
                       float yv, float rd, float ci) {
        float d;
        d = an.x - ar.x; sq = fmaf(d, d, sq);
        d = an.y - ar.y; sq = fmaf(d, d, sq);
        d = an.z - ar.z; sq = fmaf(d, d, sq);
        d = an.w - ar.w; sq = fmaf(d, d, sq);

        float lsAj = 0.f, lsAc = 0.f;
        unsigned key = 0xFFFFFFFFu;
#define COMP(ACV, AJV, APV, J)                                                 \
        { rAp += fmaxf(-(APV), 0.f);                                           \
          float acj = (ACV) - (AJV);                                           \
          lsAj += fmaxf(-acj, 0.f); lsAc += fmaxf(acj, 0.f);                   \
          unsigned kb = (__float_as_uint(fabsf(acj)) & 0xFFFFFF00u)            \
                        | (unsigned)((lane << 2) + (J));                       \
          key = key < kb ? key : kb; }
        COMP(ac.x, aj.x, ap.x, 0)
        COMP(ac.y, aj.y, ap.y, 1)
        COMP(ac.z, aj.z, ap.z, 2)
        COMP(ac.w, aj.w, ap.w, 3)
#undef COMP

        // full-wave butterfly: packed-key argmin (first-index ties) + 2 sums
#pragma unroll
        for (int s = 1; s < 64; s <<= 1) {
            unsigned ok = __shfl_xor(key, s);
            key = key < ok ? key : ok;
            lsAj += __shfl_xor(lsAj, s);
            lsAc += __shfl_xor(lsAc, s);
        }

        const int idx = (int)(key & 255u);
        const int lo  = idx >> 2;
        const int cc  = idx & 3;
        float selA = cc==0 ? aj.x : cc==1 ? aj.y : cc==2 ? aj.z : aj.w;
        float selP = cc==0 ? ap.x : cc==1 ? ap.y : cc==2 ? ap.z : ap.w;
        const float aj_at = __shfl(selA, lo);
        const float ap_at = __shfl(selP, lo);

        const float wm = (m == 0) ? 1.f : 0.f;
        const float fw = (ci > 500.f) ? 0.15f * wm : 0.f;
        if (lane == 0) {
            pen += 3.f * fmaxf(1.1f * aj_at - ap_at, 0.f);
            pen += wm * (fmaxf(8.f - lsAj, 0.f) + fmaxf(8.f - lsAc, 0.f));
            pen += fmaxf(-rd, 0.f);
            sw += wm;      sx += wm * xv;       sy += wm * yv;
            sxy = fmaf(wm * xv, yv, sxy);
            sxx = fmaf(wm * xv, xv, sxx);
            syy = fmaf(wm * yv, yv, syy);
        }
        if (lane == 63) {   // elements 252..255; end-of-curve = .w
            pen += fmaxf(aj.w - ac.w, 0.f);
            pen += fw * fmaxf(ap.w - aj.w, 0.f);
        }
    };

    // ---- software-pipelined main loop: issue next tile before consuming ----
    LOADT(A, c0) LOADS(A, c0)
#pragma unroll 1
    for (int k = 0; k < CPW; k += 2) {
        LOADT(B, c0 + k + 1) LOADS(B, c0 + k + 1)
        process(anA, arA, acA, ajA, apA, mA, xA, yA, rdA, ciA);
        if (k + 2 < CPW) { LOADT(A, c0 + k + 2) LOADS(A, c0 + k + 2) }
        process(anB, arB, acB, ajB, apB, mB, xB, yB, rdB, ciB);
    }
#undef LOADT
#undef LOADS

    // merged simple-sum stat: full-wave reduce
    float A = fmaf(sq, 10.f / (float)NTOT, rAp + pen);
#pragma unroll
    for (int s = 1; s < 64; s <<= 1) A += __shfl_xor(A, s);

    __shared__ float sred[WPB][NSTAT];
    if (lane == 0) {
        sred[wid][0] = A;   sred[wid][1] = sw;  sred[wid][2] = sx;
        sred[wid][3] = sy;  sred[wid][4] = sxy; sred[wid][5] = sxx;
        sred[wid][6] = syy;
    }
    __syncthreads();
    if (threadIdx.x == 0) {
#pragma unroll
        for (int j = 0; j < NSTAT; ++j) {
            float v = sred[0][j] + sred[1][j] + sred[2][j] + sred[3][j];
            ws[j * NBLK + blockIdx.x] = v;
        }
    }
}

__global__ __launch_bounds__(256) void loss_final(
    const float* __restrict__ ws,
    const float* __restrict__ dHaV, const float* __restrict__ dHaJ,
    const float* __restrict__ dHaT,
    const float* __restrict__ ToV,  const float* __restrict__ ToJ,
    const float* __restrict__ ToT,
    float* __restrict__ out)
{
    __shared__ float red[NSTAT][256];
    const int t = threadIdx.x;
    float p[NSTAT];
#pragma unroll
    for (int j = 0; j < NSTAT; ++j) p[j] = 0.f;
    for (int k = 0; k < NBLK / 256; ++k) {
        int b = t + k * 256;
#pragma unroll
        for (int j = 0; j < NSTAT; ++j) p[j] += ws[j * NBLK + b];
    }
#pragma unroll
    for (int j = 0; j < NSTAT; ++j) red[j][t] = p[j];
    __syncthreads();
    for (int s = 128; s > 0; s >>= 1) {
        if (t < s) {
#pragma unroll
            for (int j = 0; j < NSTAT; ++j) red[j][t] += red[j][t + s];
        }
        __syncthreads();
    }
    if (t == 0) {
        float A   = red[0][0];
        float sw  = red[1][0], sx  = red[2][0], sy  = red[3][0];
        float sxy = red[4][0], sxx = red[5][0], syy = red[6][0];

        float loss = A;

        // Pearson correlation over masked curves (one-pass identity)
        float cnum = sxy - sx * sy / sw;
        float cden = sqrtf(sxx - sx * sx / sw) * sqrtf(syy - sy * sy / sw);
        float cost = cnum / cden;
        if (!(cost == cost)) cost = 0.f;       // NaN -> 0
        cost = fminf(cost, 0.7f);
        loss += 0.7f - cost;

        float fg = 0.f;
#pragma unroll
        for (int i = 0; i < 4; ++i) {
            fg += 10.f * fmaxf(-dHaV[i], 0.f);
            fg += fmaxf(-dHaJ[i], 0.f);
            fg += fmaxf(-dHaT[i], 0.f);
            fg += fmaxf(273.15f - ToV[i], 0.f);
            fg += fmaxf(273.15f - ToJ[i], 0.f);
            fg += fmaxf(273.15f - ToT[i], 0.f);
        }
        loss += fg;

        out[0] = loss;
    }
}

extern "C" void kernel_launch(void* const* d_in, const int* in_sizes, int n_in,
                              void* d_out, int out_size, void* d_ws, size_t ws_size,
                              hipStream_t stream) {
    const float* An  = (const float*)d_in[0];
    const float* Ac  = (const float*)d_in[1];
    const float* Aj  = (const float*)d_in[2];
    const float* Ap  = (const float*)d_in[3];
    const float* Ar  = (const float*)d_in[4];
    const float* Ci  = (const float*)d_in[5];
    const float* Vc  = (const float*)d_in[6];
    const float* Jm  = (const float*)d_in[7];
    const float* Rd  = (const float*)d_in[8];
    const float* dHaV = (const float*)d_in[9];
    const float* dHaJ = (const float*)d_in[10];
    const float* dHaT = (const float*)d_in[11];
    const float* ToV  = (const float*)d_in[12];
    const float* ToJ  = (const float*)d_in[13];
    const float* ToT  = (const float*)d_in[14];
    const int*   msk  = (const int*)d_in[15];

    float* ws  = (float*)d_ws;           // NSTAT * NBLK floats = 56 KB
    float* out = (float*)d_out;

    loss_main<<<NBLK, 256, 0, stream>>>(An, Ac, Aj, Ap, Ar, Ci, Vc, Jm, Rd, msk, ws);
    loss_final<<<1, 256, 0, stream>>>(ws, dHaV, dHaJ, dHaT, ToV, ToJ, ToT, out);
}

// Round 11
// 51.199 us; speedup vs baseline: 1.3650x; 1.1517x over previous
//
#include <hip/hip_runtime.h>
#include <math.h>

// Problem geometry
#define NC   65536              // curves
#define NL   256                // points per curve
#define NTOT (NC * NL)
#define WPB  4                  // waves per block (256 threads)
#define CPW  8                  // curves per wave
#define NBLK (NC / (WPB * CPW)) // 2048 blocks
#define NSTAT 7

// stat slots: 0=A(merged) 1=sw 2=sx 3=sy 4=sxy 5=sxx 6=syy

typedef float vf4 __attribute__((ext_vector_type(4)));
__device__ __forceinline__ float4 ldnt4(const float* p) {
    vf4 v = __builtin_nontemporal_load((const vf4*)p);
    float4 r; r.x = v.x; r.y = v.y; r.z = v.z; r.w = v.w;
    return r;
}

// async global->LDS DMA, 16B per lane; LDS dest = uniform base + lane*16
__device__ __forceinline__ void gl_lds16(const float* g, float* l) {
    __builtin_amdgcn_global_load_lds(
        (const __attribute__((address_space(1))) float*)g,
        (__attribute__((address_space(3))) float*)l, 16, 0, 0);
}

__global__ __launch_bounds__(256, 3) void loss_main(
    const float* __restrict__ An, const float* __restrict__ Ac,
    const float* __restrict__ Aj, const float* __restrict__ Ap,
    const float* __restrict__ Ar, const float* __restrict__ Ci,
    const float* __restrict__ Vc, const float* __restrict__ Jm,
    const float* __restrict__ Rd, const int* __restrict__ msk,
    float* __restrict__ ws)
{
    __shared__ float ldsb[WPB][4][3][NL];   // [wave][slot][arr: Ac,Aj,Ap][elem] = 48 KB
    __shared__ float sred[WPB][NSTAT];

    const int lane = threadIdx.x & 63;
    const int wid  = threadIdx.x >> 6;
    const int c0   = (blockIdx.x * WPB + wid) * CPW;

    // accumulators
    float sq = 0.f, rAp = 0.f, pen = 0.f;
    float sw=0.f, sx=0.f, sy=0.f, sxy=0.f, sxx=0.f, syy=0.f;  // preload lanes only

    // ---- per-curve scalar preload: lane i (<CPW) owns curve c0+i ----
    float wmask = 0.f, fitw = 0.f;
    if (lane < CPW) {
        const int cc2 = c0 + lane;
        const int m = msk[cc2];
        const float x = Jm[cc2], y = Vc[cc2], rd = Rd[cc2];
        const float ci = __builtin_nontemporal_load(Ci + (size_t)cc2 * NL + (NL - 1));
        const float wm = (m == 0) ? 1.f : 0.f;
        wmask = wm;
        fitw  = (ci > 500.f) ? 0.15f * wm : 0.f;
        pen   = fmaxf(-rd, 0.f);
        sw = wm; sx = wm * x; sy = wm * y;
        sxy = wm * x * y; sxx = wm * x * x; syy = wm * y * y;
    }
    // drain scalar loads so the vmcnt ledger below is exact
    asm volatile("s_waitcnt vmcnt(0)" ::: "memory");

    // rotating register buffers for the nt An/Ar streams
    float4 an0, an1, an2, an3, ar0, ar1, ar2, ar3;

#define STAGE(S, c) {                                                          \
        const size_t o_ = (size_t)(c) * NL + (size_t)(lane << 2);              \
        an##S = ldnt4(An + o_);  ar##S = ldnt4(Ar + o_);                       \
        gl_lds16(Ac + o_, &ldsb[wid][S][0][0]);                                \
        gl_lds16(Aj + o_, &ldsb[wid][S][1][0]);                                \
        gl_lds16(Ap + o_, &ldsb[wid][S][2][0]); }

#define COMP(ACV, AJV, APV, J)                                                 \
        { rAp += fmaxf(-(APV), 0.f);                                           \
          float acj = (ACV) - (AJV);                                           \
          lsAj += fmaxf(-acj, 0.f); lsAc += fmaxf(acj, 0.f);                   \
          unsigned kb = (__float_as_uint(fabsf(acj)) & 0xFFFFFF00u)            \
                        | (unsigned)((lane << 2) + (J));                       \
          key = key < kb ? key : kb; }

#define PROCESS(an, ar, ac, aj, ap, kk) {                                      \
        float d;                                                               \
        d = an.x - ar.x; sq = fmaf(d, d, sq);                                  \
        d = an.y - ar.y; sq = fmaf(d, d, sq);                                  \
        d = an.z - ar.z; sq = fmaf(d, d, sq);                                  \
        d = an.w - ar.w; sq = fmaf(d, d, sq);                                  \
        float lsAj = 0.f, lsAc = 0.f;                                          \
        unsigned key = 0xFFFFFFFFu;                                            \
        COMP(ac.x, aj.x, ap.x, 0)                                              \
        COMP(ac.y, aj.y, ap.y, 1)                                              \
        COMP(ac.z, aj.z, ap.z, 2)                                              \
        COMP(ac.w, aj.w, ap.w, 3)                                              \
        _Pragma("unroll")                                                      \
        for (int s = 1; s < 64; s <<= 1) {                                     \
            unsigned ok = __shfl_xor(key, s);                                  \
            key = key < ok ? key : ok;                                         \
            lsAj += __shfl_xor(lsAj, s);                                       \
            lsAc += __shfl_xor(lsAc, s);                                       \
        }                                                                      \
        const int idx = (int)(key & 255u);                                     \
        const int lo  = idx >> 2;                                              \
        const int cc  = idx & 3;                                               \
        float selA = cc==0 ? aj.x : cc==1 ? aj.y : cc==2 ? aj.z : aj.w;        \
        float selP = cc==0 ? ap.x : cc==1 ? ap.y : cc==2 ? ap.z : ap.w;        \
        const float aj_at = __shfl(selA, lo);                                  \
        const float ap_at = __shfl(selP, lo);                                  \
        const float wv = __shfl(wmask, kk);                                    \
        const float fw = __shfl(fitw,  kk);                                    \
        if (lane == 0) {                                                       \
            pen += 3.f * fmaxf(1.1f * aj_at - ap_at, 0.f);                     \
            pen += wv * (fmaxf(8.f - lsAj, 0.f) + fmaxf(8.f - lsAc, 0.f));     \
        }                                                                      \
        if (lane == 63) {                                                      \
            pen += fmaxf(aj.w - ac.w, 0.f);                                    \
            pen += fw * fmaxf(ap.w - aj.w, 0.f);                               \
        } }

#define ITER(S, W, STAGE_STMT, kk) {                                           \
        asm volatile("s_waitcnt vmcnt(" #W ")" ::: "memory");                  \
        const int li_ = lane << 2;                                             \
        float4 ac = *(const float4*)&ldsb[wid][S][0][li_];                     \
        float4 aj = *(const float4*)&ldsb[wid][S][1][li_];                     \
        float4 ap = *(const float4*)&ldsb[wid][S][2][li_];                     \
        asm volatile("s_waitcnt lgkmcnt(0)" ::: "memory");                     \
        STAGE_STMT;                                                            \
        PROCESS(an##S, ar##S, ac, aj, ap, kk) }

    // ---- prologue: stage 4 curves (20 vmcnt ops in flight) ----
    STAGE(0, c0 + 0)
    STAGE(1, c0 + 1)
    STAGE(2, c0 + 2)
    STAGE(3, c0 + 3)

    // ---- 8 pipelined iterations, 4-deep ----
    ITER(0, 15, STAGE(0, c0 + 4), 0)
    ITER(1, 15, STAGE(1, c0 + 5), 1)
    ITER(2, 15, STAGE(2, c0 + 6), 2)
    ITER(3, 15, STAGE(3, c0 + 7), 3)
    ITER(0, 15, , 4)
    ITER(1, 10, , 5)
    ITER(2, 5,  , 6)
    ITER(3, 0,  , 7)

#undef ITER
#undef PROCESS
#undef COMP
#undef STAGE

    // merged simple-sum stat + corr stats: full-wave reduce
    float A = fmaf(sq, 10.f / (float)NTOT, rAp + pen);
#pragma unroll
    for (int s = 1; s < 64; s <<= 1) {
        A   += __shfl_xor(A,   s);
        sw  += __shfl_xor(sw,  s);
        sx  += __shfl_xor(sx,  s);
        sy  += __shfl_xor(sy,  s);
        sxy += __shfl_xor(sxy, s);
        sxx += __shfl_xor(sxx, s);
        syy += __shfl_xor(syy, s);
    }

    if (lane == 0) {
        sred[wid][0] = A;   sred[wid][1] = sw;  sred[wid][2] = sx;
        sred[wid][3] = sy;  sred[wid][4] = sxy; sred[wid][5] = sxx;
        sred[wid][6] = syy;
    }
    __syncthreads();
    if (threadIdx.x == 0) {
#pragma unroll
        for (int j = 0; j < NSTAT; ++j) {
            float v = sred[0][j] + sred[1][j] + sred[2][j] + sred[3][j];
            ws[j * NBLK + blockIdx.x] = v;
        }
    }
}

__global__ __launch_bounds__(256) void loss_final(
    const float* __restrict__ ws,
    const float* __restrict__ dHaV, const float* __restrict__ dHaJ,
    const float* __restrict__ dHaT,
    const float* __restrict__ ToV,  const float* __restrict__ ToJ,
    const float* __restrict__ ToT,
    float* __restrict__ out)
{
    __shared__ float red[NSTAT][256];
    const int t = threadIdx.x;
    float p[NSTAT];
#pragma unroll
    for (int j = 0; j < NSTAT; ++j) p[j] = 0.f;
    for (int k = 0; k < NBLK / 256; ++k) {
        int b = t + k * 256;
#pragma unroll
        for (int j = 0; j < NSTAT; ++j) p[j] += ws[j * NBLK + b];
    }
#pragma unroll
    for (int j = 0; j < NSTAT; ++j) red[j][t] = p[j];
    __syncthreads();
    for (int s = 128; s > 0; s >>= 1) {
        if (t < s) {
#pragma unroll
            for (int j = 0; j < NSTAT; ++j) red[j][t] += red[j][t + s];
        }
        __syncthreads();
    }
    if (t == 0) {
        float A   = red[0][0];
        float sw  = red[1][0], sx  = red[2][0], sy  = red[3][0];
        float sxy = red[4][0], sxx = red[5][0], syy = red[6][0];

        float loss = A;

        // Pearson correlation over masked curves (one-pass identity)
        float cnum = sxy - sx * sy / sw;
        float cden = sqrtf(sxx - sx * sx / sw) * sqrtf(syy - sy * sy / sw);
        float cost = cnum / cden;
        if (!(cost == cost)) cost = 0.f;       // NaN -> 0
        cost = fminf(cost, 0.7f);
        loss += 0.7f - cost;

        float fg = 0.f;
#pragma unroll
        for (int i = 0; i < 4; ++i) {
            fg += 10.f * fmaxf(-dHaV[i], 0.f);
            fg += fmaxf(-dHaJ[i], 0.f);
            fg += fmaxf(-dHaT[i], 0.f);
            fg += fmaxf(273.15f - ToV[i], 0.f);
            fg += fmaxf(273.15f - ToJ[i], 0.f);
            fg += fmaxf(273.15f - ToT[i], 0.f);
        }
        loss += fg;

        out[0] = loss;
    }
}

extern "C" void kernel_launch(void* const* d_in, const int* in_sizes, int n_in,
                              void* d_out, int out_size, void* d_ws, size_t ws_size,
                              hipStream_t stream) {
    const float* An  = (const float*)d_in[0];
    const float* Ac  = (const float*)d_in[1];
    const float* Aj  = (const float*)d_in[2];
    const float* Ap  = (const float*)d_in[3];
    const float* Ar  = (const float*)d_in[4];
    const float* Ci  = (const float*)d_in[5];
    const float* Vc  = (const float*)d_in[6];
    const float* Jm  = (const float*)d_in[7];
    const float* Rd  = (const float*)d_in[8];
    const float* dHaV = (const float*)d_in[9];
    const float* dHaJ = (const float*)d_in[10];
    const float* dHaT = (const float*)d_in[11];
    const float* ToV  = (const float*)d_in[12];
    const float* ToJ  = (const float*)d_in[13];
    const float* ToT  = (const float*)d_in[14];
    const int*   msk  = (const int*)d_in[15];

    float* ws  = (float*)d_ws;           // NSTAT * NBLK floats = 56 KB
    float* out = (float*)d_out;

    loss_main<<<NBLK, 256, 0, stream>>>(An, Ac, Aj, Ap, Ar, Ci, Vc, Jm, Rd, msk, ws);
    loss_final<<<1, 256, 0, stream>>>(ws, dHaV, dHaJ, dHaT, ToV, ToJ, ToT, out);
}